// Round 9
// baseline (459.129 us; speedup 1.0000x reference)
//
#include <hip/hip_runtime.h>
#include <cstdint>
#include <cstddef>

#define N_INST 100
#define HW (640 * 960)          /* 614400 */
#define PIX_THR 0.4f
#define FRAC_THR 0.03f
#define EPS_BORDER 5e-5f        /* |sm - 0.4| window -> exact repair path */
#define FLAG_CAP 65536
#define L2E 1.4426950408889634f

#define CB 1200                 /* compute blocks (4 px/thread * 128 thr) */
#define ZB 480                  /* zero-writer blocks (measured optimum)  */
#define GRID (CB + ZB)
#define CHUNK_F4 15360          /* 128 thr * 120 iters */
#define CHUNK_ITER 120
#define NCHUNK 1000             /* 15,360,000 float4 total */

// d_out layout (float32):
//   [0 .. 100)                      cls_prob_s
//   [100 .. 100+N*HW)               keep_masks
//   [100+N*HW .. +100)              cls_idx_s (as float)
//   [100+N*HW+100 .. +100)          keep_flags (0/1 float)
#define OUT_MASKS_OFF 100
#define OUT_CLSIDX_OFF (100 + (size_t)N_INST * HW)
#define OUT_FLAGS_OFF (100 + (size_t)N_INST * HW + N_INST)

// ws layout:
//   [0]        int    ord[100]        sorted pos -> original idx
//   [512]      int    rank[100]       original idx -> sorted pos
//   [1024]     int    keep[100]
//   [1536]     uint   mask_sum[100]
//   [2048]     uint   flag_count
//   [2052]     uint   zctr            zero-chunk queue head
//   [2056]     uint   done            last-block-done counter
//   [4096]     uint   pair_cnt[100*100]    (40000 B)
//   [65536]    uint4  pvals[HW]            {code, vlo, vhi, 0} (9.83 MB)
//   [9895936]  uint   flag_list[FLAG_CAP]

__global__ __launch_bounds__(256) void k0_init(
    const float* __restrict__ cls_prob,
    const int* __restrict__ cls_idx,
    int* __restrict__ ord,
    int* __restrict__ rank_arr,
    float* __restrict__ out,
    unsigned* __restrict__ mask_sum,
    unsigned* __restrict__ ctrs,          /* flag_count, zctr, done */
    unsigned* __restrict__ pair_cnt) {
    int t = threadIdx.x;
    if (t < N_INST) {
        float pi = cls_prob[t];
        int rank = 0;
        for (int j = 0; j < N_INST; ++j) {
            float pj = cls_prob[j];
            rank += (pj > pi) || (pj == pi && j < t);
        }
        ord[rank] = t;
        rank_arr[t] = rank;
        out[rank] = pi;
        out[OUT_CLSIDX_OFF + rank] = (float)cls_idx[t];
        mask_sum[t] = 0u;
    }
    if (t < 3) ctrs[t] = 0u;
    for (int i = t; i < N_INST * N_INST; i += 256)
        pair_cnt[i] = 0u;
}

// Mega kernel (R6 role-split + in-kernel epilogue):
//   blocks [0, CB): one pass over the 245.8 MB logits (4 px/thread float4,
//     no-max exp2 softmax, comparison-exact top-2; border px -> flag list).
//   all blocks then drain the zero-chunk queue (writers [CB,GRID) start at
//   t=0), streaming 245.8 MB of zeros into d_out's mask region.
//   Last-block-done epilogue (R8's proven handoff, moved in-kernel): the
//   dynamically-last block runs the bit-exact repair of flagged pixels
//   (two-pass streaming, low VGPR) and the greedy NMS scan (pair_cnt read
//   straight from L2 -> no 40 KB LDS -> no kernel-wide occupancy hit).
__global__ __launch_bounds__(128) void k1_mega(
    const float* __restrict__ mask,
    const int* __restrict__ rank_arr,
    const int* __restrict__ ord,
    const int* __restrict__ cls_idx,
    unsigned* __restrict__ mask_sum,
    unsigned* __restrict__ pair_cnt,
    uint4* __restrict__ pvals,
    unsigned* __restrict__ flag_count,
    unsigned* __restrict__ flag_list,
    unsigned* __restrict__ zctr,
    unsigned* __restrict__ done,
    int* __restrict__ keep,
    float* __restrict__ out) {
    int t = threadIdx.x;
    __shared__ unsigned s_chunk;
    __shared__ unsigned s_last;
    __shared__ int s_i[N_INST];        // srank (compute) / sord (epilogue)
    __shared__ unsigned s_u[N_INST];   // ssum (compute) / sms (epilogue)
    __shared__ int scls[N_INST];
    __shared__ int skp[N_INST];

    // ================= compute role =================
    if (blockIdx.x < CB) {
        if (t < N_INST) {
            s_i[t] = rank_arr[t];
            s_u[t] = 0u;
        }
        __syncthreads();

        int p0 = (blockIdx.x * 128 + t) * 4;
        const float* base = mask + p0;

        float S[4] = {0.0f, 0.0f, 0.0f, 0.0f};
        float m[4] = {-3.4e38f, -3.4e38f, -3.4e38f, -3.4e38f};
        float n[4] = {-3.4e38f, -3.4e38f, -3.4e38f, -3.4e38f};
        int ia[4] = {0, 0, 0, 0};
        int ib[4] = {0, 0, 0, 0};

#pragma unroll 10
        for (int i = 0; i < N_INST; ++i) {
            float4 v4 = *(const float4*)(base + (size_t)i * HW);
            float vv[4] = {v4.x, v4.y, v4.z, v4.w};
#pragma unroll
            for (int j = 0; j < 4; ++j) {
                float v = vv[j];
                S[j] += exp2f(v * L2E);               // chain: add only
                bool gt = v > m[j];
                bool g2 = v > n[j];
                n[j] = fmaxf(n[j], fminf(m[j], v));   // med3(m, n, v)
                ib[j] = gt ? ia[j] : (g2 ? i : ib[j]);
                ia[j] = gt ? i : ia[j];
                m[j] = fmaxf(m[j], v);
            }
        }

#pragma unroll
        for (int j = 0; j < 4; ++j) {
            int p = p0 + j;
            float e1 = exp2f(m[j] * L2E);
            float e2 = exp2f(n[j] * L2E);
            float t04 = 0.4f * S[j];
            float w = EPS_BORDER * S[j];
            bool q1 = e1 >= t04;
            bool border = (fabsf(e1 - t04) < w) || (q1 && fabsf(e2 - t04) < w);

            unsigned c = 0u;
            float vlo = 0.0f, vhi = 0.0f;
            if (border) {
                unsigned slot = atomicAdd(flag_count, 1u);
                if (slot < FLAG_CAP) flag_list[slot] = (unsigned)p;
            } else if (q1) {
                bool q2 = e2 >= t04;
                int r1 = s_i[ia[j]];
                atomicAdd(&s_u[r1], 1u);
                if (q2) {
                    int r2 = s_i[ib[j]];
                    atomicAdd(&s_u[r2], 1u);
                    int lo = min(r1, r2), hi = max(r1, r2);
                    atomicAdd(&pair_cnt[lo * N_INST + hi], 1u);
                    c = (unsigned)(lo + 1) | ((unsigned)(hi + 1) << 8);
                    vlo = (r1 < r2) ? m[j] : n[j];
                    vhi = (r1 < r2) ? n[j] : m[j];
                } else {
                    c = (unsigned)(r1 + 1);
                    vlo = m[j];
                }
            }
            pvals[p] = make_uint4(c, __float_as_uint(vlo), __float_as_uint(vhi), 0u);
        }

        __syncthreads();
        if (t < N_INST && s_u[t] != 0u)
            atomicAdd(&mask_sum[t], s_u[t]);
    }

    // ================= zero-chunk drain =================
    for (;;) {
        if (t == 0) s_chunk = atomicAdd(zctr, 1u);
        __syncthreads();
        unsigned c = s_chunk;
        __syncthreads();
        if (c >= NCHUNK) break;
        float4* dst = (float4*)(out + OUT_MASKS_OFF) + (size_t)c * CHUNK_F4 + t;
        const float4 z4 = make_float4(0.0f, 0.0f, 0.0f, 0.0f);
#pragma unroll 8
        for (int k = 0; k < CHUNK_ITER; ++k)
            dst[k * 128] = z4;
    }

    // ================= last-block-done handoff =================
    __threadfence();
    if (t == 0) s_last = atomicAdd(done, 1u);
    __syncthreads();
    if (s_last != GRID - 1) return;
    __threadfence();   // acquire side

    // ---- epilogue 1: bit-exact repair (two-pass streaming, low VGPR) ----
    if (t < N_INST) s_i[t] = ord[t];
    __syncthreads();
    unsigned nf = *flag_count;
    if (nf > FLAG_CAP) nf = FLAG_CAP;
    for (unsigned idx = t; idx < nf; idx += 128) {
        int p = (int)flag_list[idx];
        // pass 1: exact max / top-2 in sorted order
        float m = -3.4e38f, m2 = -3.4e38f;
        int p1 = 0, p2 = 0;
        for (int i = 0; i < N_INST; ++i) {
            float v = mask[(size_t)s_i[i] * HW + p];
            if (v > m) { m2 = m; p2 = p1; m = v; p1 = i; }
            else if (v > m2) { m2 = v; p2 = i; }
        }
        // pass 2: sequential ordered denominator (reference arithmetic)
        float d = 0.0f;
        for (int i = 0; i < N_INST; ++i) {
            float v = mask[(size_t)s_i[i] * HW + p];
            d += expf(v - m);
        }
        float sm1 = 1.0f / d;
        float sm2 = expf(m2 - m) / d;
        bool q1 = (sm1 >= PIX_THR);
        bool q2 = (sm2 >= PIX_THR);
        unsigned c = 0u;
        float vlo = 0.0f, vhi = 0.0f;
        if (q1) {
            atomicAdd(&mask_sum[p1], 1u);
            if (q2) {
                atomicAdd(&mask_sum[p2], 1u);
                int lo = min(p1, p2), hi = max(p1, p2);
                atomicAdd(&pair_cnt[lo * N_INST + hi], 1u);
                c = (unsigned)(lo + 1) | ((unsigned)(hi + 1) << 8);
                vlo = (lo == p1) ? m : m2;
                vhi = (lo == p1) ? m2 : m;
            } else {
                c = (unsigned)(p1 + 1);
                vlo = m;
            }
        }
        pvals[p] = make_uint4(c, __float_as_uint(vlo), __float_as_uint(vhi), 0u);
    }
    __syncthreads();
    __threadfence();

    // ---- epilogue 2: greedy NMS scan (pair_cnt from L2, no big LDS) ----
    if (t < N_INST) {
        scls[t] = cls_idx[s_i[t]];
        s_u[t] = mask_sum[t];
    }
    __syncthreads();

    for (int b = 0; b < N_INST; ++b) {
        if (t < 64) {
            unsigned cnt = 0u;
            for (int a = t; a < b; a += 64)
                if (skp[a] && scls[a] == scls[b])
                    cnt += pair_cnt[a * N_INST + b];
#pragma unroll
            for (int off = 32; off; off >>= 1)
                cnt += __shfl_down((int)cnt, off);
            if (t == 0) {
                unsigned ms = s_u[b];
                float overlap = (float)cnt / fmaxf((float)ms, 1.0f);
                bool degen = (ms == 0u) || (ms == (unsigned)HW);
                bool skip = degen || (overlap > FRAC_THR);
                skp[b] = skip ? 0 : 1;
            }
        }
        __syncthreads();
    }

    if (t < N_INST) {
        keep[t] = skp[t];
        out[OUT_FLAGS_OFF + t] = (float)skp[t];
    }
}

// Sparse scatter: zeros were streamed by k1_mega; write only assigned
// pixels from the pvals record. Separate dispatch -> pvals/keep reads are
// visibility-safe via the dispatch boundary.
__global__ __launch_bounds__(256) void k3_scatter(
    const uint4* __restrict__ pvals,
    const int* __restrict__ keep,
    float* __restrict__ out) {
    __shared__ int skeep[N_INST];
    if (threadIdx.x < N_INST) skeep[threadIdx.x] = keep[threadIdx.x];
    __syncthreads();

    int p = blockIdx.x * 256 + threadIdx.x;
    uint4 pv = pvals[p];
    unsigned c = pv.x;
    if (c == 0u) return;
    int a = (int)(c & 0xFFu) - 1;
    int b = (int)(c >> 8) - 1;

    int inst;
    float val;
    if (skeep[a]) {
        inst = a;
        val = __uint_as_float(pv.y);
    } else if (b >= 0 && skeep[b]) {
        inst = b;
        val = __uint_as_float(pv.z);
    } else {
        return;
    }
    out[OUT_MASKS_OFF + (size_t)inst * HW + p] = val;
}

extern "C" void kernel_launch(void* const* d_in, const int* in_sizes, int n_in,
                              void* d_out, int out_size, void* d_ws, size_t ws_size,
                              hipStream_t stream) {
    const float* cls_prob = (const float*)d_in[0];
    const float* mask = (const float*)d_in[1];
    const int* cls_idx = (const int*)d_in[2];
    float* out = (float*)d_out;

    char* ws = (char*)d_ws;
    int* ord = (int*)(ws + 0);
    int* rank_arr = (int*)(ws + 512);
    int* keep = (int*)(ws + 1024);
    unsigned* mask_sum = (unsigned*)(ws + 1536);
    unsigned* ctrs = (unsigned*)(ws + 2048);      // [0]=flag_count [1]=zctr [2]=done
    unsigned* pair_cnt = (unsigned*)(ws + 4096);
    uint4* pvals = (uint4*)(ws + 65536);
    unsigned* flag_list = (unsigned*)(ws + 65536 + (size_t)HW * 16);

    unsigned* flag_count = &ctrs[0];
    unsigned* zctr = &ctrs[1];
    unsigned* done = &ctrs[2];

    k0_init<<<1, 256, 0, stream>>>(cls_prob, cls_idx, ord, rank_arr, out,
                                   mask_sum, ctrs, pair_cnt);
    k1_mega<<<GRID, 128, 0, stream>>>(mask, rank_arr, ord, cls_idx, mask_sum,
                                      pair_cnt, pvals, flag_count, flag_list,
                                      zctr, done, keep, out);
    k3_scatter<<<HW / 256, 256, 0, stream>>>(pvals, keep, out);
}

// Round 10
// 253.755 us; speedup vs baseline: 1.8093x; 1.8093x over previous
//
#include <hip/hip_runtime.h>
#include <cstdint>
#include <cstddef>

#define N_INST 100
#define HW (640 * 960)          /* 614400 */
#define PIX_THR 0.4f
#define FRAC_THR 0.03f
#define EPS_BORDER 5e-5f        /* |sm - 0.4| window -> exact repair path */
#define FLAG_CAP 65536
#define L2E 1.4426950408889634f

#define CB 1200                 /* compute blocks (4 px/thread * 128 thr) */
#define ZB 480                  /* zero-writer blocks (measured optimum)  */
#define GRID (CB + ZB)
#define CHUNK_F4 15360          /* 128 thr * 120 iters */
#define CHUNK_ITER 120
#define NCHUNK 1000             /* 15,360,000 float4 total */
#define FIN_BLOCKS 128

// d_out layout (float32):
//   [0 .. 100)                      cls_prob_s
//   [100 .. 100+N*HW)               keep_masks
//   [100+N*HW .. +100)              cls_idx_s (as float)
//   [100+N*HW+100 .. +100)          keep_flags (0/1 float)
#define OUT_MASKS_OFF 100
#define OUT_CLSIDX_OFF (100 + (size_t)N_INST * HW)
#define OUT_FLAGS_OFF (100 + (size_t)N_INST * HW + N_INST)

// ws layout:
//   [0]        int    ord[100]        sorted pos -> original idx
//   [512]      int    rank[100]       original idx -> sorted pos
//   [1024]     int    keep[100]
//   [1536]     uint   mask_sum[100]
//   [2048]     uint   flag_count
//   [2052]     uint   zctr            zero-chunk queue head
//   [2056]     uint   done            finish-kernel block counter
//   [4096]     uint   pair_cnt[100*100]    (40000 B)
//   [65536]    uint4  pvals[HW]            {code, vlo, vhi, 0} (9.83 MB)
//   [9895936]  uint   flag_list[FLAG_CAP]

__global__ __launch_bounds__(256) void k0_init(
    const float* __restrict__ cls_prob,
    const int* __restrict__ cls_idx,
    int* __restrict__ ord,
    int* __restrict__ rank_arr,
    float* __restrict__ out,
    unsigned* __restrict__ mask_sum,
    unsigned* __restrict__ ctrs,          /* flag_count, zctr, done */
    unsigned* __restrict__ pair_cnt) {
    int t = threadIdx.x;
    if (t < N_INST) {
        float pi = cls_prob[t];
        int rank = 0;
        for (int j = 0; j < N_INST; ++j) {
            float pj = cls_prob[j];
            rank += (pj > pi) || (pj == pi && j < t);
        }
        ord[rank] = t;
        rank_arr[t] = rank;
        out[rank] = pi;
        out[OUT_CLSIDX_OFF + rank] = (float)cls_idx[t];
        mask_sum[t] = 0u;
    }
    if (t < 3) ctrs[t] = 0u;
    for (int i = t; i < N_INST * N_INST; i += 256)
        pair_cnt[i] = 0u;
}

// Role-split fused kernel. Compute blocks [0,CB) run the one-pass softmax
// classification and EXIT (they do not join the drain — 1680 concurrent
// writers measured slower than ~480 on the d_out write path). Writer blocks
// [CB,GRID) drain the full zero-chunk queue, streaming 245.8 MB of zeros
// into d_out's mask region concurrently with the compute blocks' reads.
__global__ __launch_bounds__(128) void k1_fused(
    const float* __restrict__ mask,
    const int* __restrict__ rank_arr,
    unsigned* __restrict__ mask_sum,
    unsigned* __restrict__ pair_cnt,
    uint4* __restrict__ pvals,
    unsigned* __restrict__ flag_count,
    unsigned* __restrict__ flag_list,
    unsigned* __restrict__ zctr,
    float* __restrict__ out) {
    int t = threadIdx.x;

    if (blockIdx.x < CB) {
        // ---- compute role ----
        __shared__ int srank[N_INST];
        __shared__ unsigned ssum[N_INST];
        if (t < N_INST) {
            srank[t] = rank_arr[t];
            ssum[t] = 0u;
        }
        __syncthreads();

        int p0 = (blockIdx.x * 128 + t) * 4;
        const float* base = mask + p0;

        float S[4] = {0.0f, 0.0f, 0.0f, 0.0f};
        float m[4] = {-3.4e38f, -3.4e38f, -3.4e38f, -3.4e38f};
        float n[4] = {-3.4e38f, -3.4e38f, -3.4e38f, -3.4e38f};
        int ia[4] = {0, 0, 0, 0};
        int ib[4] = {0, 0, 0, 0};

#pragma unroll 10
        for (int i = 0; i < N_INST; ++i) {
            float4 v4 = *(const float4*)(base + (size_t)i * HW);
            float vv[4] = {v4.x, v4.y, v4.z, v4.w};
#pragma unroll
            for (int j = 0; j < 4; ++j) {
                float v = vv[j];
                S[j] += exp2f(v * L2E);               // chain: add only
                bool gt = v > m[j];
                bool g2 = v > n[j];
                n[j] = fmaxf(n[j], fminf(m[j], v));   // med3(m, n, v)
                ib[j] = gt ? ia[j] : (g2 ? i : ib[j]);
                ia[j] = gt ? i : ia[j];
                m[j] = fmaxf(m[j], v);
            }
        }

#pragma unroll
        for (int j = 0; j < 4; ++j) {
            int p = p0 + j;
            float e1 = exp2f(m[j] * L2E);
            float e2 = exp2f(n[j] * L2E);
            float t04 = 0.4f * S[j];
            float w = EPS_BORDER * S[j];
            bool q1 = e1 >= t04;
            bool border = (fabsf(e1 - t04) < w) || (q1 && fabsf(e2 - t04) < w);

            unsigned c = 0u;
            float vlo = 0.0f, vhi = 0.0f;
            if (border) {
                unsigned slot = atomicAdd(flag_count, 1u);
                if (slot < FLAG_CAP) flag_list[slot] = (unsigned)p;
            } else if (q1) {
                bool q2 = e2 >= t04;
                int r1 = srank[ia[j]];
                atomicAdd(&ssum[r1], 1u);
                if (q2) {
                    int r2 = srank[ib[j]];
                    atomicAdd(&ssum[r2], 1u);
                    int lo = min(r1, r2), hi = max(r1, r2);
                    atomicAdd(&pair_cnt[lo * N_INST + hi], 1u);
                    c = (unsigned)(lo + 1) | ((unsigned)(hi + 1) << 8);
                    vlo = (r1 < r2) ? m[j] : n[j];
                    vhi = (r1 < r2) ? n[j] : m[j];
                } else {
                    c = (unsigned)(r1 + 1);
                    vlo = m[j];
                }
            }
            pvals[p] = make_uint4(c, __float_as_uint(vlo), __float_as_uint(vhi), 0u);
        }

        __syncthreads();
        if (t < N_INST && ssum[t] != 0u)
            atomicAdd(&mask_sum[t], ssum[t]);
        return;   // compute blocks exit — do NOT contend on the write path
    }

    // ---- writer role: drain the whole zero-chunk queue ----
    __shared__ unsigned s_chunk;
    for (;;) {
        if (t == 0) s_chunk = atomicAdd(zctr, 1u);
        __syncthreads();
        unsigned c = s_chunk;
        __syncthreads();
        if (c >= NCHUNK) break;
        float4* dst = (float4*)(out + OUT_MASKS_OFF) + (size_t)c * CHUNK_F4 + t;
        const float4 z4 = make_float4(0.0f, 0.0f, 0.0f, 0.0f);
#pragma unroll 8
        for (int k = 0; k < CHUNK_ITER; ++k)
            dst[k * 128] = z4;
    }
}

// Repair + scan in ONE dispatch (R8-proven last-block-done pattern):
// all blocks grid-stride the flagged pixels with the bit-exact reference
// arithmetic (v[100] register-cached, high parallelism); each block fences
// and increments `done`; the dynamically-last block runs the greedy NMS
// scan. No spin, no co-residency assumption.
__global__ __launch_bounds__(256) void k2_finish(
    const float* __restrict__ mask,
    const int* __restrict__ ord,
    const int* __restrict__ cls_idx,
    unsigned* __restrict__ mask_sum,
    unsigned* __restrict__ pair_cnt,
    uint4* __restrict__ pvals,
    const unsigned* __restrict__ flag_count,
    const unsigned* __restrict__ flag_list,
    unsigned* __restrict__ done,
    int* __restrict__ keep,
    float* __restrict__ out) {
    __shared__ int sord[N_INST];
    __shared__ unsigned s_last;
    int t = threadIdx.x;
    if (t < N_INST) sord[t] = ord[t];
    __syncthreads();

    // ---- phase 1: bit-exact repair of flagged pixels ----
    unsigned nf = *flag_count;
    if (nf > FLAG_CAP) nf = FLAG_CAP;
    for (unsigned idx = blockIdx.x * 256 + t; idx < nf;
         idx += FIN_BLOCKS * 256) {
        int p = (int)flag_list[idx];
        float v[N_INST];
#pragma unroll
        for (int i = 0; i < N_INST; ++i)
            v[i] = mask[(size_t)sord[i] * HW + p];

        float m = v[0];
        int p1 = 0;
        float m2 = -3.4e38f;
        int p2 = 0;
#pragma unroll
        for (int i = 1; i < N_INST; ++i) {
            if (v[i] > m) { m2 = m; p2 = p1; m = v[i]; p1 = i; }
            else if (v[i] > m2) { m2 = v[i]; p2 = i; }
        }
        float d = 0.0f;
#pragma unroll
        for (int i = 0; i < N_INST; ++i)
            d += expf(v[i] - m);

        float sm1 = 1.0f / d;
        float sm2 = expf(m2 - m) / d;
        bool q1 = (sm1 >= PIX_THR);
        bool q2 = (sm2 >= PIX_THR);
        unsigned c = 0u;
        float vlo = 0.0f, vhi = 0.0f;
        if (q1) {
            atomicAdd(&mask_sum[p1], 1u);
            if (q2) {
                atomicAdd(&mask_sum[p2], 1u);
                int lo = min(p1, p2), hi = max(p1, p2);
                atomicAdd(&pair_cnt[lo * N_INST + hi], 1u);
                c = (unsigned)(lo + 1) | ((unsigned)(hi + 1) << 8);
                vlo = v[lo];
                vhi = v[hi];
            } else {
                c = (unsigned)(p1 + 1);
                vlo = v[p1];
            }
        }
        pvals[p] = make_uint4(c, __float_as_uint(vlo), __float_as_uint(vhi), 0u);
    }

    // ---- handoff: release our work, elect the last block ----
    __threadfence();
    if (t == 0) s_last = atomicAdd(done, 1u);
    __syncthreads();
    if (s_last != FIN_BLOCKS - 1) return;
    __threadfence();   // acquire side

    // ---- phase 2 (last block only): greedy NMS scan ----
    __shared__ unsigned spair[N_INST * N_INST];   // 40 KB
    __shared__ int scls[N_INST];
    __shared__ unsigned sms[N_INST];
    __shared__ int skeep[N_INST];
    for (int i = t; i < N_INST * N_INST; i += 256)
        spair[i] = pair_cnt[i];
    if (t < N_INST) {
        scls[t] = cls_idx[sord[t]];
        sms[t] = mask_sum[t];
    }
    __syncthreads();

    for (int b = 0; b < N_INST; ++b) {
        if (t < 64) {
            unsigned cnt = 0u;
            for (int a = t; a < b; a += 64)
                if (skeep[a] && scls[a] == scls[b])
                    cnt += spair[a * N_INST + b];
#pragma unroll
            for (int off = 32; off; off >>= 1)
                cnt += __shfl_down((int)cnt, off);
            if (t == 0) {
                unsigned ms = sms[b];
                float overlap = (float)cnt / fmaxf((float)ms, 1.0f);
                bool degen = (ms == 0u) || (ms == (unsigned)HW);
                bool skip = degen || (overlap > FRAC_THR);
                skeep[b] = skip ? 0 : 1;
            }
        }
        __syncthreads();
    }

    if (t < N_INST) {
        keep[t] = skeep[t];
        out[OUT_FLAGS_OFF + t] = (float)skeep[t];
    }
}

// Sparse scatter: zeros were streamed by k1_fused's writer blocks; write
// only assigned pixels from the pvals record. Separate dispatch -> pvals/
// keep reads are visibility-safe via the dispatch boundary.
__global__ __launch_bounds__(256) void k3_scatter(
    const uint4* __restrict__ pvals,
    const int* __restrict__ keep,
    float* __restrict__ out) {
    __shared__ int skeep[N_INST];
    if (threadIdx.x < N_INST) skeep[threadIdx.x] = keep[threadIdx.x];
    __syncthreads();

    int p = blockIdx.x * 256 + threadIdx.x;
    uint4 pv = pvals[p];
    unsigned c = pv.x;
    if (c == 0u) return;
    int a = (int)(c & 0xFFu) - 1;
    int b = (int)(c >> 8) - 1;

    int inst;
    float val;
    if (skeep[a]) {
        inst = a;
        val = __uint_as_float(pv.y);
    } else if (b >= 0 && skeep[b]) {
        inst = b;
        val = __uint_as_float(pv.z);
    } else {
        return;
    }
    out[OUT_MASKS_OFF + (size_t)inst * HW + p] = val;
}

extern "C" void kernel_launch(void* const* d_in, const int* in_sizes, int n_in,
                              void* d_out, int out_size, void* d_ws, size_t ws_size,
                              hipStream_t stream) {
    const float* cls_prob = (const float*)d_in[0];
    const float* mask = (const float*)d_in[1];
    const int* cls_idx = (const int*)d_in[2];
    float* out = (float*)d_out;

    char* ws = (char*)d_ws;
    int* ord = (int*)(ws + 0);
    int* rank_arr = (int*)(ws + 512);
    int* keep = (int*)(ws + 1024);
    unsigned* mask_sum = (unsigned*)(ws + 1536);
    unsigned* ctrs = (unsigned*)(ws + 2048);      // [0]=flag_count [1]=zctr [2]=done
    unsigned* pair_cnt = (unsigned*)(ws + 4096);
    uint4* pvals = (uint4*)(ws + 65536);
    unsigned* flag_list = (unsigned*)(ws + 65536 + (size_t)HW * 16);

    unsigned* flag_count = &ctrs[0];
    unsigned* zctr = &ctrs[1];
    unsigned* done = &ctrs[2];

    k0_init<<<1, 256, 0, stream>>>(cls_prob, cls_idx, ord, rank_arr, out,
                                   mask_sum, ctrs, pair_cnt);
    k1_fused<<<GRID, 128, 0, stream>>>(mask, rank_arr, mask_sum, pair_cnt,
                                       pvals, flag_count, flag_list, zctr, out);
    k2_finish<<<FIN_BLOCKS, 256, 0, stream>>>(mask, ord, cls_idx, mask_sum,
                                              pair_cnt, pvals, flag_count,
                                              flag_list, done, keep, out);
    k3_scatter<<<HW / 256, 256, 0, stream>>>(pvals, keep, out);
}